// Round 1
// baseline (447.878 us; speedup 1.0000x reference)
//
// BitNetAttention on MI355X (gfx950)
// Pipeline:
//  1) reductions: absmax(hidden), mean|W| for Wq/Wk/Wv/Wo  (deterministic 2-phase)
//  2) RoPE cos/sin tables (fp64 -> fp32, matches numpy fp32 trig to ~1ulp)
//  3) quantize: x -> int8-valued bf16, W -> ternary bf16 (exact in bf16)
//  4) GEMM (bf16 MFMA 16x16x32, exact integer arithmetic): QKV proj + RoPE epilogue
//     Q,K stored bf16 [b,h,s,64]; V stored fp32 [b,h,s,64]
//  5) V transpose+split kernel: -> Vt_hi/Vt_lo bf16 [b,h,64,s]
//  6) attention: per block (b,h,qtile=64 rows), 4 waves x 16 rows
//     pass A: QK^T (bf16 MFMA) -> online row max m / sumexp l
//     pass B: recompute QK^T, p=exp(s-m)/l -> write attn_weights (d_out),
//             split p to bf16 hi/lo via per-wave LDS, PV with 3-MFMA split precision
//  7) absmax(attn_pre) -> quantize -> GEMM O-proj -> d_out[0]
// Workspace requirement: ~89 MB (see WS_NEED).

#include <hip/hip_runtime.h>
#include <math.h>

typedef __attribute__((ext_vector_type(8))) short short8;
typedef __attribute__((ext_vector_type(4))) float f32x4;
typedef __attribute__((ext_vector_type(4))) unsigned int u32x4;

#define DEV __device__ __forceinline__

static constexpr int B_ = 2, S_ = 2048, H_ = 16, D_ = 64, DM_ = 1024;
static constexpr int BH_ = B_ * H_;        // 32
static constexpr int NQ_ = B_ * S_;        // 4096
static constexpr size_t OUT0_ELEMS = (size_t)NQ_ * DM_;  // 4,194,304

// ---- workspace byte offsets ----
static constexpr size_t OFF_PMAXX = 256;                                   // 256 f32
static constexpr size_t OFF_PSUM  = 1280;                                  // 4x128 f32
static constexpr size_t OFF_PMAXA = 4096;                                  // 256 f32
static constexpr size_t OFF_COS   = 8192;                                  // 2048*32 f32
static constexpr size_t OFF_SIN   = OFF_COS + (size_t)S_ * 32 * 4;
static constexpr size_t OFF_XQ    = (size_t)1 << 20;                       // bf16 [4096][1024]
static constexpr size_t OFF_WQ3   = OFF_XQ   + (size_t)NQ_ * DM_ * 2;      // bf16 [3072][1024]
static constexpr size_t OFF_WO    = OFF_WQ3  + (size_t)3072 * 1024 * 2;    // bf16 [1024][1024]
static constexpr size_t OFF_QB    = OFF_WO   + (size_t)1024 * 1024 * 2;    // bf16 [bh][s][64]
static constexpr size_t OFF_KB    = OFF_QB   + (size_t)BH_ * S_ * D_ * 2;
static constexpr size_t OFF_VF    = OFF_KB   + (size_t)BH_ * S_ * D_ * 2;  // f32 [bh][s][64]
static constexpr size_t OFF_VTHI  = OFF_VF   + (size_t)BH_ * S_ * D_ * 4;  // bf16 [bh][64][s]
static constexpr size_t OFF_VTLO  = OFF_VTHI + (size_t)BH_ * D_ * S_ * 2;
static constexpr size_t OFF_APRE  = OFF_VTLO + (size_t)BH_ * D_ * S_ * 2;  // f32 [4096][1024]
static constexpr size_t OFF_AQ    = OFF_APRE + (size_t)NQ_ * DM_ * 4;      // bf16 [4096][1024]
static constexpr size_t WS_NEED   = OFF_AQ   + (size_t)NQ_ * DM_ * 2;      // ~89 MB

DEV unsigned short f2bf(float f) {  // round-to-nearest-even f32 -> bf16
  unsigned u = __builtin_bit_cast(unsigned, f);
  return (unsigned short)((u + 0x7fffu + ((u >> 16) & 1u)) >> 16);
}
DEV float bf2f(unsigned short h) {
  unsigned u = ((unsigned)h) << 16;
  return __builtin_bit_cast(float, u);
}
DEV void gload16(const void* g, void* l) {
  __builtin_amdgcn_global_load_lds((const __attribute__((address_space(1))) unsigned int*)g,
                                   (__attribute__((address_space(3))) unsigned int*)l, 16, 0, 0);
}

// ---------------- reductions ----------------
__global__ void k_absmax(const float* __restrict__ x, int n4, float* __restrict__ out) {
  __shared__ float red[256];
  const float4* xv = (const float4*)x;
  float mv = 0.f;
  for (int i = blockIdx.x * blockDim.x + threadIdx.x; i < n4; i += gridDim.x * blockDim.x) {
    float4 v = xv[i];
    mv = fmaxf(mv, fmaxf(fmaxf(fabsf(v.x), fabsf(v.y)), fmaxf(fabsf(v.z), fabsf(v.w))));
  }
  red[threadIdx.x] = mv;
  __syncthreads();
  for (int st = 128; st > 0; st >>= 1) {
    if ((int)threadIdx.x < st) red[threadIdx.x] = fmaxf(red[threadIdx.x], red[threadIdx.x + st]);
    __syncthreads();
  }
  if (threadIdx.x == 0) out[blockIdx.x] = red[0];
}

__global__ void k_abssum(const float* __restrict__ x, int n4, float* __restrict__ out) {
  __shared__ float red[256];
  const float4* xv = (const float4*)x;
  float s = 0.f;
  for (int i = blockIdx.x * blockDim.x + threadIdx.x; i < n4; i += gridDim.x * blockDim.x) {
    float4 v = xv[i];
    s += fabsf(v.x) + fabsf(v.y) + fabsf(v.z) + fabsf(v.w);
  }
  red[threadIdx.x] = s;
  __syncthreads();
  for (int st = 128; st > 0; st >>= 1) {
    if ((int)threadIdx.x < st) red[threadIdx.x] += red[threadIdx.x + st];
    __syncthreads();
  }
  if (threadIdx.x == 0) out[blockIdx.x] = red[0];
}

__global__ void k_finalize1(float* __restrict__ wsf) {
  if (threadIdx.x != 0) return;
  const float* pmax = wsf + OFF_PMAXX / 4;
  const float* psum = wsf + OFF_PSUM / 4;
  float m = 0.f;
  for (int i = 0; i < 256; ++i) m = fmaxf(m, pmax[i]);
  wsf[0] = m / 127.0f;  // s_x
  for (int k = 0; k < 4; ++k) {
    float s = 0.f;
    for (int i = 0; i < 128; ++i) s += psum[k * 128 + i];
    wsf[1 + k] = s / 1048576.0f;  // s_wq, s_wk, s_wv, s_wo
  }
}

__global__ void k_finalize2(float* __restrict__ wsf) {
  if (threadIdx.x != 0) return;
  const float* pmax = wsf + OFF_PMAXA / 4;
  float m = 0.f;
  for (int i = 0; i < 256; ++i) m = fmaxf(m, pmax[i]);
  wsf[5] = m / 127.0f;  // s_a
}

// ---------------- RoPE tables ----------------
__global__ void k_rope(float* __restrict__ cosT, float* __restrict__ sinT) {
  int i = blockIdx.x * 256 + threadIdx.x;  // 2048*32
  int s = i >> 5, f = i & 31;
  double inv = pow(10000.0, -(double)(2 * f) / 64.0);
  float th = (float)s * (float)inv;  // fp32 product, as reference einsum
  cosT[i] = (float)cos((double)th);
  sinT[i] = (float)sin((double)th);
}

// ---------------- quantizers ----------------
__global__ void k_quant_act(const float* __restrict__ x, const float* __restrict__ scal, int sidx,
                            unsigned short* __restrict__ out, int n4) {
  int i = blockIdx.x * 256 + threadIdx.x;
  if (i >= n4) return;
  float sc = scal[sidx];
  float4 v = ((const float4*)x)[i];
  ushort4 o;
  o.x = f2bf(fminf(fmaxf(rintf(v.x / sc), -127.f), 127.f));
  o.y = f2bf(fminf(fmaxf(rintf(v.y / sc), -127.f), 127.f));
  o.z = f2bf(fminf(fmaxf(rintf(v.z / sc), -127.f), 127.f));
  o.w = f2bf(fminf(fmaxf(rintf(v.w / sc), -127.f), 127.f));
  ((ushort4*)out)[i] = o;
}

__global__ void k_quant_w(const float* __restrict__ x, const float* __restrict__ scal, int sidx,
                          unsigned short* __restrict__ out, int n4) {
  int i = blockIdx.x * 256 + threadIdx.x;
  if (i >= n4) return;
  float sc = scal[sidx];
  float4 v = ((const float4*)x)[i];
  ushort4 o;
  o.x = f2bf(fminf(fmaxf(rintf(v.x / sc), -1.f), 1.f));
  o.y = f2bf(fminf(fmaxf(rintf(v.y / sc), -1.f), 1.f));
  o.z = f2bf(fminf(fmaxf(rintf(v.z / sc), -1.f), 1.f));
  o.w = f2bf(fminf(fmaxf(rintf(v.w / sc), -1.f), 1.f));
  ((ushort4*)out)[i] = o;
}

// ---------------- GEMM: C[M][N] = A[M][1024] * B[N][1024]^T (bf16 MFMA, exact ints) ----------------
// MODE 0: QKV projection (N=3072): epilogue scales, applies RoPE to q/k, writes Qb/Kb (bf16) and Vf (f32)
// MODE 1: O projection  (N=1024): epilogue scales, writes fp32 to Co
template <int MODE>
__launch_bounds__(256, 2)
__global__ void k_gemm(const unsigned short* __restrict__ Ag, const unsigned short* __restrict__ Bg,
                       const float* __restrict__ scal, const float* __restrict__ cosT,
                       const float* __restrict__ sinT, unsigned short* __restrict__ Qb,
                       unsigned short* __restrict__ Kb, float* __restrict__ Vf,
                       float* __restrict__ Co) {
  __shared__ alignas(16) unsigned short As[128 * 64];
  __shared__ alignas(16) unsigned short Bs[128 * 64];
  const int w = threadIdx.x >> 6, l = threadIdx.x & 63;
  const int mbase = blockIdx.y * 128, nbase = blockIdx.x * 128;

  const f32x4 vzero = {0.f, 0.f, 0.f, 0.f};
  f32x4 acc[4][4];
#pragma unroll
  for (int a = 0; a < 4; ++a)
#pragma unroll
    for (int b = 0; b < 4; ++b) acc[a][b] = vzero;

  const int srow = l >> 3;
  const int sxor = ((l & 7) << 4) ^ ((l >> 3) << 4);  // source pre-swizzle (LDS stays linear)

  for (int kt = 0; kt < 16; ++kt) {
    __syncthreads();
#pragma unroll
    for (int i = 0; i < 4; ++i) {
      int j = (w << 2) + i;  // 16 chunks of 8 rows each, per tile
      int rowA = mbase + (j << 3) + srow;
      gload16((const char*)Ag + (size_t)rowA * 2048 + kt * 128 + sxor, (char*)As + (j << 10));
      int rowB = nbase + (j << 3) + srow;
      gload16((const char*)Bg + (size_t)rowB * 2048 + kt * 128 + sxor, (char*)Bs + (j << 10));
    }
    asm volatile("s_waitcnt vmcnt(0)" ::: "memory");
    __syncthreads();

    const int rA0 = ((w >> 1) << 6) + (l & 15);
    const int rB0 = ((w & 1) << 6) + (l & 15);
#pragma unroll
    for (int c = 0; c < 2; ++c) {
      const int colb = (c << 6) + ((l >> 4) << 4);
      short8 af[4], bf[4];
#pragma unroll
      for (int t = 0; t < 4; ++t) {
        const int ra = rA0 + (t << 4);
        af[t] = *(const short8*)((const char*)As + ra * 128 + (colb ^ ((ra & 7) << 4)));
        const int rb = rB0 + (t << 4);
        bf[t] = *(const short8*)((const char*)Bs + rb * 128 + (colb ^ ((rb & 7) << 4)));
      }
#pragma unroll
      for (int mt = 0; mt < 4; ++mt)
#pragma unroll
        for (int nt = 0; nt < 4; ++nt)
          acc[mt][nt] = __builtin_amdgcn_mfma_f32_16x16x32_bf16(af[mt], bf[nt], acc[mt][nt], 0, 0, 0);
    }
  }

  // epilogue  (C layout: col = lane&15, row = (lane>>4)*4 + reg)
  if constexpr (MODE == 0) {
    const int wm = w >> 1, wn = w & 1;
    const int gcolbase = nbase + wn * 64;  // 64-aligned -> single head per wave
    const int section = gcolbase >> 10;    // 0=q 1=k 2=v
    const int h = (gcolbase & 1023) >> 6;
    const float sc = scal[0] * scal[1 + section];
    const int growbase = mbase + wm * 64;
    if (section < 2) {
      unsigned short* Outb = (section == 0) ? Qb : Kb;
#pragma unroll
      for (int mt = 0; mt < 4; ++mt)
#pragma unroll
        for (int r = 0; r < 4; ++r) {
          const int grow = growbase + mt * 16 + ((l >> 4) << 2) + r;
          const int b = grow >> 11, s = grow & 2047;
          const size_t ob = ((size_t)(b * 16 + h) * 2048 + s) * 64;
#pragma unroll
          for (int nt = 0; nt < 2; ++nt) {
            const int d = nt * 16 + (l & 15);  // d < 32; pair is d+32 in tile nt+2
            const float v1 = acc[mt][nt][r] * sc;
            const float v2 = acc[mt][nt + 2][r] * sc;
            const float cv = cosT[s * 32 + d];
            const float sv = sinT[s * 32 + d];
            Outb[ob + d] = f2bf(v1 * cv - v2 * sv);
            Outb[ob + d + 32] = f2bf(v2 * cv + v1 * sv);
          }
        }
    } else {
#pragma unroll
      for (int mt = 0; mt < 4; ++mt)
#pragma unroll
        for (int r = 0; r < 4; ++r) {
          const int grow = growbase + mt * 16 + ((l >> 4) << 2) + r;
          const int b = grow >> 11, s = grow & 2047;
          const size_t ob = ((size_t)(b * 16 + h) * 2048 + s) * 64;
#pragma unroll
          for (int nt = 0; nt < 4; ++nt) Vf[ob + nt * 16 + (l & 15)] = acc[mt][nt][r] * sc;
        }
    }
  } else {
    const float sc = scal[4] * scal[5];
#pragma unroll
    for (int mt = 0; mt < 4; ++mt)
#pragma unroll
      for (int r = 0; r < 4; ++r) {
        const int grow = mbase + (w >> 1) * 64 + mt * 16 + ((l >> 4) << 2) + r;
#pragma unroll
        for (int nt = 0; nt < 4; ++nt) {
          const int gcol = nbase + (w & 1) * 64 + nt * 16 + (l & 15);
          Co[(size_t)grow * 1024 + gcol] = acc[mt][nt][r] * sc;
        }
      }
  }
}

// ---------------- V transpose + bf16 hi/lo split ----------------
__global__ void k_transpose_v(const float* __restrict__ Vf, unsigned short* __restrict__ Vthi,
                              unsigned short* __restrict__ Vtlo) {
  __shared__ float t[64][65];
  const int bh = blockIdx.x >> 5, st = blockIdx.x & 31;
  const float* src = Vf + ((size_t)bh * 2048 + st * 64) * 64;
  const int tid = threadIdx.x;
  for (int i = tid; i < 1024; i += 256) {
    float4 v = ((const float4*)src)[i];
    int row = i >> 4, c4 = (i & 15) << 2;
    t[row][c4] = v.x; t[row][c4 + 1] = v.y; t[row][c4 + 2] = v.z; t[row][c4 + 3] = v.w;
  }
  __syncthreads();
  const int d = tid >> 2, sp = (tid & 3) << 4;
  const size_t ob = ((size_t)bh * 64 + d) * 2048 + st * 64 + sp;
  for (int j = 0; j < 16; ++j) {
    float f = t[sp + j][d];
    unsigned short hi = f2bf(f);
    unsigned short lo = f2bf(f - bf2f(hi));
    Vthi[ob + j] = hi;
    Vtlo[ob + j] = lo;
  }
}

// ---------------- attention ----------------
__launch_bounds__(256, 2)
__global__ void k_attn(const unsigned short* __restrict__ Qb, const unsigned short* __restrict__ Kb,
                       const unsigned short* __restrict__ Vhi, const unsigned short* __restrict__ Vlo,
                       const float* __restrict__ scal, float* __restrict__ Wout,
                       float* __restrict__ Apre) {
  __shared__ alignas(16) unsigned short Ks[64 * 64];
  __shared__ alignas(16) unsigned short Vhs[64 * 64];
  __shared__ alignas(16) unsigned short Vls[64 * 64];
  __shared__ alignas(16) unsigned int Ps[4][16 * 64];

  const int bh = blockIdx.x >> 5, qt = blockIdx.x & 31;
  const int w = threadIdx.x >> 6, l = threadIdx.x & 63;

  const unsigned short* Kg = Kb + (size_t)bh * S_ * D_;
  const unsigned short* Vhg = Vhi + (size_t)bh * D_ * S_;
  const unsigned short* Vlg = Vlo + (size_t)bh * D_ * S_;

  // Q fragments (A-operand): row = l&15, k = 8*(l>>4)+j (+32 per chunk)
  short8 aq[2];
  {
    const int qrow_f = qt * 64 + w * 16 + (l & 15);
    const unsigned short* qp = Qb + (size_t)bh * S_ * D_ + (size_t)qrow_f * D_ + ((l >> 4) << 3);
    aq[0] = *(const short8*)qp;
    aq[1] = *(const short8*)(qp + 32);
  }

  const f32x4 vzero = {0.f, 0.f, 0.f, 0.f};
  float m[4], ls[4];
#pragma unroll
  for (int r = 0; r < 4; ++r) { m[r] = -INFINITY; ls[r] = 0.f; }

  const int kxor = ((l & 7) << 4) ^ ((l >> 3) << 4);

  // ===== PASS A: row max + sumexp =====
  for (int kb = 0; kb < 32; ++kb) {
    __syncthreads();
    {
      const char* baseK = (const char*)(Kg + (size_t)kb * 64 * D_);  // contiguous 8KB tile
#pragma unroll
      for (int i = 0; i < 2; ++i) {
        int j = (w << 1) + i;
        gload16(baseK + (j << 10) + ((l << 4) ^ ((l >> 3) << 4)), (char*)Ks + (j << 10));
      }
    }
    asm volatile("s_waitcnt vmcnt(0)" ::: "memory");
    __syncthreads();

    f32x4 sa[4];
#pragma unroll
    for (int t = 0; t < 4; ++t) sa[t] = vzero;
#pragma unroll
    for (int c = 0; c < 2; ++c) {
      const int colb = (c << 6) + ((l >> 4) << 4);
      short8 bk[4];
#pragma unroll
      for (int ct = 0; ct < 4; ++ct) {
        const int rb = (ct << 4) + (l & 15);
        bk[ct] = *(const short8*)((const char*)Ks + rb * 128 + (colb ^ ((rb & 7) << 4)));
      }
#pragma unroll
      for (int ct = 0; ct < 4; ++ct)
        sa[ct] = __builtin_amdgcn_mfma_f32_16x16x32_bf16(aq[c], bk[ct], sa[ct], 0, 0, 0);
    }
#pragma unroll
    for (int r = 0; r < 4; ++r) {
      float tm = fmaxf(fmaxf(sa[0][r], sa[1][r]), fmaxf(sa[2][r], sa[3][r]));
#pragma unroll
      for (int off = 1; off < 16; off <<= 1) tm = fmaxf(tm, __shfl_xor(tm, off));
      const float mn = fmaxf(m[r], tm * 0.125f);
      const float corr = __expf(m[r] - mn);
      float rs = __expf(sa[0][r] * 0.125f - mn) + __expf(sa[1][r] * 0.125f - mn) +
                 __expf(sa[2][r] * 0.125f - mn) + __expf(sa[3][r] * 0.125f - mn);
#pragma unroll
      for (int off = 1; off < 16; off <<= 1) rs += __shfl_xor(rs, off);
      ls[r] = ls[r] * corr + rs;
      m[r] = mn;
    }
  }

  float rl[4];
#pragma unroll
  for (int r = 0; r < 4; ++r) rl[r] = 1.0f / ls[r];

  f32x4 oacc[4];
#pragma unroll
  for (int t = 0; t < 4; ++t) oacc[t] = vzero;
  unsigned int* Pw = &Ps[w][0];
  const size_t wb0 = (size_t)bh * S_ * S_;

  // ===== PASS B: p write + PV (split precision) =====
  for (int kb = 0; kb < 32; ++kb) {
    __syncthreads();
    {
      const char* baseK = (const char*)(Kg + (size_t)kb * 64 * D_);
#pragma unroll
      for (int i = 0; i < 2; ++i) {
        int j = (w << 1) + i;
        gload16(baseK + (j << 10) + ((l << 4) ^ ((l >> 3) << 4)), (char*)Ks + (j << 10));
        const size_t voff = (size_t)(j * 8 + (l >> 3)) * (S_ * 2) + (size_t)kb * 128 + kxor;
        gload16((const char*)Vhg + voff, (char*)Vhs + (j << 10));
        gload16((const char*)Vlg + voff, (char*)Vls + (j << 10));
      }
    }
    asm volatile("s_waitcnt vmcnt(0)" ::: "memory");
    __syncthreads();

    f32x4 sa[4];
#pragma unroll
    for (int t = 0; t < 4; ++t) sa[t] = vzero;
#pragma unroll
    for (int c = 0; c < 2; ++c) {
      const int colb = (c << 6) + ((l >> 4) << 4);
      short8 bk[4];
#pragma unroll
      for (int ct = 0; ct < 4; ++ct) {
        const int rb = (ct << 4) + (l & 15);
        bk[ct] = *(const short8*)((const char*)Ks + rb * 128 + (colb ^ ((rb & 7) << 4)));
      }
#pragma unroll
      for (int ct = 0; ct < 4; ++ct)
        sa[ct] = __builtin_amdgcn_mfma_f32_16x16x32_bf16(aq[c], bk[ct], sa[ct], 0, 0, 0);
    }

    // p = exp(s - m)/l : write to attn_weights, pack hi/lo into per-wave LDS
#pragma unroll
    for (int ct = 0; ct < 4; ++ct) {
#pragma unroll
      for (int r = 0; r < 4; ++r) {
        const int qr = qt * 64 + w * 16 + ((l >> 4) << 2) + r;
        const float p = __expf(sa[ct][r] * 0.125f - m[r]) * rl[r];
        Wout[wb0 + (size_t)qr * S_ + (size_t)(kb * 64 + ct * 16 + (l & 15))] = p;
        const unsigned short hi = f2bf(p);
        const unsigned short lo = f2bf(p - bf2f(hi));
        const int prow = ((l >> 4) << 2) + r;
        const int pcolb = (ct * 16 + (l & 15)) << 2;
        *(unsigned int*)((char*)Pw + prow * 256 + (pcolb ^ ((prow & 7) << 4))) =
            (((unsigned)hi) << 16) | (unsigned)lo;
      }
    }

    // PV: O += (p_hi+p_lo)*(v_hi+v_lo), dropping lo*lo
#pragma unroll
    for (int c = 0; c < 2; ++c) {
      const int arow = l & 15;
      const int abyte = (c << 7) + ((l >> 4) << 5);
      const u32x4 u0 = *(const u32x4*)((const char*)Pw + arow * 256 + (abyte ^ ((arow & 7) << 4)));
      const u32x4 u1 =
          *(const u32x4*)((const char*)Pw + arow * 256 + ((abyte + 16) ^ ((arow & 7) << 4)));
      short8 ph, pl;
#pragma unroll
      for (int i2 = 0; i2 < 4; ++i2) {
        ph[i2] = (short)(u0[i2] >> 16);
        pl[i2] = (short)(u0[i2] & 0xffffu);
        ph[4 + i2] = (short)(u1[i2] >> 16);
        pl[4 + i2] = (short)(u1[i2] & 0xffffu);
      }
      const int colb = (c << 6) + ((l >> 4) << 4);
#pragma unroll
      for (int dt = 0; dt < 4; ++dt) {
        const int rv = (dt << 4) + (l & 15);
        const short8 vh = *(const short8*)((const char*)Vhs + rv * 128 + (colb ^ ((rv & 7) << 4)));
        const short8 vl = *(const short8*)((const char*)Vls + rv * 128 + (colb ^ ((rv & 7) << 4)));
        oacc[dt] = __builtin_amdgcn_mfma_f32_16x16x32_bf16(ph, vh, oacc[dt], 0, 0, 0);
        oacc[dt] = __builtin_amdgcn_mfma_f32_16x16x32_bf16(pl, vh, oacc[dt], 0, 0, 0);
        oacc[dt] = __builtin_amdgcn_mfma_f32_16x16x32_bf16(ph, vl, oacc[dt], 0, 0, 0);
      }
    }
  }

  const int b = bh >> 4, h = bh & 15;
#pragma unroll
  for (int dt = 0; dt < 4; ++dt)
#pragma unroll
    for (int r = 0; r < 4; ++r) {
      const int qr = qt * 64 + w * 16 + ((l >> 4) << 2) + r;
      Apre[(size_t)(b * S_ + qr) * DM_ + h * 64 + dt * 16 + (l & 15)] = oacc[dt][r];
    }
}

// ---------------- launcher ----------------
extern "C" void kernel_launch(void* const* d_in, const int* in_sizes, int n_in, void* d_out,
                              int out_size, void* d_ws, size_t ws_size, hipStream_t stream) {
  const float* hidden = (const float*)d_in[0];
  const float* Wq = (const float*)d_in[1];
  const float* Wk = (const float*)d_in[2];
  const float* Wv = (const float*)d_in[3];
  const float* Wo = (const float*)d_in[4];
  float* out0 = (float*)d_out;
  float* out1 = out0 + OUT0_ELEMS;

  if (ws_size < WS_NEED) return;  // need ~89 MB scratch

  char* ws = (char*)d_ws;
  float* wsf = (float*)ws;
  float* pmaxx = (float*)(ws + OFF_PMAXX);
  float* psum = (float*)(ws + OFF_PSUM);
  float* pmaxa = (float*)(ws + OFF_PMAXA);
  float* cosT = (float*)(ws + OFF_COS);
  float* sinT = (float*)(ws + OFF_SIN);
  unsigned short* xq = (unsigned short*)(ws + OFF_XQ);
  unsigned short* wq3 = (unsigned short*)(ws + OFF_WQ3);
  unsigned short* wo = (unsigned short*)(ws + OFF_WO);
  unsigned short* Qbp = (unsigned short*)(ws + OFF_QB);
  unsigned short* Kbp = (unsigned short*)(ws + OFF_KB);
  float* Vfp = (float*)(ws + OFF_VF);
  unsigned short* Vthip = (unsigned short*)(ws + OFF_VTHI);
  unsigned short* Vtlop = (unsigned short*)(ws + OFF_VTLO);
  float* apre = (float*)(ws + OFF_APRE);
  float* aqp = (unsigned short*)(ws + OFF_AQ) ? (float*)nullptr : nullptr;  // (unused placeholder)
  unsigned short* aq16 = (unsigned short*)(ws + OFF_AQ);

  k_absmax<<<256, 256, 0, stream>>>(hidden, 1048576, pmaxx);
  k_abssum<<<128, 256, 0, stream>>>(Wq, 262144, psum + 0);
  k_abssum<<<128, 256, 0, stream>>>(Wk, 262144, psum + 128);
  k_abssum<<<128, 256, 0, stream>>>(Wv, 262144, psum + 256);
  k_abssum<<<128, 256, 0, stream>>>(Wo, 262144, psum + 384);
  k_finalize1<<<1, 64, 0, stream>>>(wsf);
  k_rope<<<256, 256, 0, stream>>>(cosT, sinT);
  k_quant_act<<<4096, 256, 0, stream>>>(hidden, wsf, 0, xq, 1048576);
  k_quant_w<<<1024, 256, 0, stream>>>(Wq, wsf, 1, wq3, 262144);
  k_quant_w<<<1024, 256, 0, stream>>>(Wk, wsf, 2, wq3 + 1024 * 1024, 262144);
  k_quant_w<<<1024, 256, 0, stream>>>(Wv, wsf, 3, wq3 + 2 * 1024 * 1024, 262144);
  k_quant_w<<<1024, 256, 0, stream>>>(Wo, wsf, 4, wo, 262144);
  k_gemm<0><<<dim3(24, 32), 256, 0, stream>>>(xq, wq3, wsf, cosT, sinT, Qbp, Kbp, Vfp, nullptr);
  k_transpose_v<<<1024, 256, 0, stream>>>(Vfp, Vthip, Vtlop);
  k_attn<<<1024, 256, 0, stream>>>(Qbp, Kbp, Vthip, Vtlop, wsf, out1, apre);
  k_absmax<<<256, 256, 0, stream>>>(apre, 1048576, pmaxa);
  k_finalize2<<<1, 64, 0, stream>>>(wsf);
  k_quant_act<<<4096, 256, 0, stream>>>(apre, wsf, 5, aq16, 1048576);
  k_gemm<1><<<dim3(8, 32), 256, 0, stream>>>(aq16, wo, wsf, nullptr, nullptr, nullptr, nullptr,
                                             nullptr, out0);
  (void)aqp; (void)in_sizes; (void)n_in; (void)out_size;
}

// Round 2
// 382.716 us; speedup vs baseline: 1.1703x; 1.1703x over previous
//
// BitNetAttention on MI355X (gfx950) — round 2
//  - pass A softmax uses precomputed Cauchy-Schwarz bound c_r = |q_r|*kmax/8 (no online max,
//    no per-tile cross-lane reduces); row norms computed in GEMM-0 epilogue for free
//  - 2-phase double-buffered staging (single barrier/tile) in attn + both GEMMs
//  - coalesced float4 attn-weight stores reconstructed from the per-wave LDS P-tile
//  - launch count 19 -> 12 (fused abssum x4, quant_w x4, absmax(apre) folded into attn)

#include <hip/hip_runtime.h>
#include <math.h>

typedef __attribute__((ext_vector_type(8))) short short8;
typedef __attribute__((ext_vector_type(4))) float f32x4;
typedef __attribute__((ext_vector_type(4))) unsigned int u32x4;

#define DEV __device__ __forceinline__

static constexpr int B_ = 2, S_ = 2048, H_ = 16, D_ = 64, DM_ = 1024;
static constexpr int BH_ = B_ * H_;        // 32
static constexpr int NQ_ = B_ * S_;        // 4096
static constexpr size_t OUT0_ELEMS = (size_t)NQ_ * DM_;

// ---- workspace byte offsets ----
static constexpr size_t OFF_PMAXX = 256;                                   // 128 f32
static constexpr size_t OFF_PSUM  = 1280;                                  // 4x128 f32
static constexpr size_t OFF_PMAXA = 4096;                                  // 1024 f32
static constexpr size_t OFF_K2M   = 12288;                                 // 32 f32
static constexpr size_t OFF_COS   = 16384;                                 // 2048*32 f32
static constexpr size_t OFF_SIN   = OFF_COS + (size_t)S_ * 32 * 4;
static constexpr size_t OFF_Q2    = OFF_SIN + (size_t)S_ * 32 * 4;         // f32 [bh][2048]
static constexpr size_t OFF_K2    = OFF_Q2 + (size_t)BH_ * S_ * 4;
static constexpr size_t OFF_XQ    = OFF_K2 + (size_t)BH_ * S_ * 4;         // bf16 [4096][1024]
static constexpr size_t OFF_WQ3   = OFF_XQ   + (size_t)NQ_ * DM_ * 2;      // bf16 [3072][1024]
static constexpr size_t OFF_WO    = OFF_WQ3  + (size_t)3072 * 1024 * 2;    // bf16 [1024][1024]
static constexpr size_t OFF_QB    = OFF_WO   + (size_t)1024 * 1024 * 2;    // bf16 [bh][s][64]
static constexpr size_t OFF_KB    = OFF_QB   + (size_t)BH_ * S_ * D_ * 2;
static constexpr size_t OFF_VF    = OFF_KB   + (size_t)BH_ * S_ * D_ * 2;  // f32 [bh][s][64]
static constexpr size_t OFF_VTHI  = OFF_VF   + (size_t)BH_ * S_ * D_ * 4;  // bf16 [bh][64][s]
static constexpr size_t OFF_VTLO  = OFF_VTHI + (size_t)BH_ * D_ * S_ * 2;
static constexpr size_t OFF_APRE  = OFF_VTLO + (size_t)BH_ * D_ * S_ * 2;  // f32 [4096][1024]
static constexpr size_t OFF_AQ    = OFF_APRE + (size_t)NQ_ * DM_ * 4;      // bf16 [4096][1024]
static constexpr size_t WS_NEED   = OFF_AQ   + (size_t)NQ_ * DM_ * 2;      // ~89 MB

DEV unsigned short f2bf(float f) {
  unsigned u = __builtin_bit_cast(unsigned, f);
  return (unsigned short)((u + 0x7fffu + ((u >> 16) & 1u)) >> 16);
}
DEV float bf2f(unsigned short h) {
  unsigned u = ((unsigned)h) << 16;
  return __builtin_bit_cast(float, u);
}
DEV void gload16(const void* g, void* l) {
  __builtin_amdgcn_global_load_lds((const __attribute__((address_space(1))) unsigned int*)g,
                                   (__attribute__((address_space(3))) unsigned int*)l, 16, 0, 0);
}

// ---------------- fused first-stage reductions ----------------
// y==0: absmax(hidden) -> pmaxx[0..127];  y=1..4: abssum(W[y-1]) -> psum[(y-1)*128 + bx]
__global__ void k_reduce5(const float* __restrict__ x, const float* __restrict__ w0,
                          const float* __restrict__ w1, const float* __restrict__ w2,
                          const float* __restrict__ w3, float* __restrict__ pmaxx,
                          float* __restrict__ psum) {
  __shared__ float red[256];
  const int y = blockIdx.y;
  if (y == 0) {
    const float4* xv = (const float4*)x;
    float mv = 0.f;
    for (int i = blockIdx.x * 256 + threadIdx.x; i < 1048576; i += 128 * 256) {
      float4 v = xv[i];
      mv = fmaxf(mv, fmaxf(fmaxf(fabsf(v.x), fabsf(v.y)), fmaxf(fabsf(v.z), fabsf(v.w))));
    }
    red[threadIdx.x] = mv;
    __syncthreads();
    for (int st = 128; st > 0; st >>= 1) {
      if ((int)threadIdx.x < st) red[threadIdx.x] = fmaxf(red[threadIdx.x], red[threadIdx.x + st]);
      __syncthreads();
    }
    if (threadIdx.x == 0) pmaxx[blockIdx.x] = red[0];
  } else {
    const float* wsrc = (y == 1) ? w0 : (y == 2) ? w1 : (y == 3) ? w2 : w3;
    const float4* xv = (const float4*)wsrc;
    float s = 0.f;
    for (int i = blockIdx.x * 256 + threadIdx.x; i < 262144; i += 128 * 256) {
      float4 v = xv[i];
      s += fabsf(v.x) + fabsf(v.y) + fabsf(v.z) + fabsf(v.w);
    }
    red[threadIdx.x] = s;
    __syncthreads();
    for (int st = 128; st > 0; st >>= 1) {
      if ((int)threadIdx.x < st) red[threadIdx.x] += red[threadIdx.x + st];
      __syncthreads();
    }
    if (threadIdx.x == 0) psum[(y - 1) * 128 + blockIdx.x] = red[0];
  }
}

__global__ void k_finalize1(float* __restrict__ wsf) {
  if (threadIdx.x != 0) return;
  const float* pmax = wsf + OFF_PMAXX / 4;
  const float* psum = wsf + OFF_PSUM / 4;
  float m = 0.f;
  for (int i = 0; i < 128; ++i) m = fmaxf(m, pmax[i]);
  wsf[0] = m / 127.0f;  // s_x
  for (int k = 0; k < 4; ++k) {
    float s = 0.f;
    for (int i = 0; i < 128; ++i) s += psum[k * 128 + i];
    wsf[1 + k] = s / 1048576.0f;  // s_wq, s_wk, s_wv, s_wo
  }
}

__global__ void k_finalize2(const float* __restrict__ pmaxa, float* __restrict__ wsf) {
  __shared__ float red[256];
  float m = 0.f;
  for (int i = threadIdx.x; i < 1024; i += 256) m = fmaxf(m, pmaxa[i]);
  red[threadIdx.x] = m;
  __syncthreads();
  for (int st = 128; st > 0; st >>= 1) {
    if ((int)threadIdx.x < st) red[threadIdx.x] = fmaxf(red[threadIdx.x], red[threadIdx.x + st]);
    __syncthreads();
  }
  if (threadIdx.x == 0) wsf[5] = red[0] / 127.0f;  // s_a
}

// ---------------- RoPE tables ----------------
__global__ void k_rope(float* __restrict__ cosT, float* __restrict__ sinT) {
  int i = blockIdx.x * 256 + threadIdx.x;
  int s = i >> 5, f = i & 31;
  double inv = pow(10000.0, -(double)(2 * f) / 64.0);
  float th = (float)s * (float)inv;
  cosT[i] = (float)cos((double)th);
  sinT[i] = (float)sin((double)th);
}

// ---------------- quantizers ----------------
__global__ void k_quant_act(const float* __restrict__ x, const float* __restrict__ scal, int sidx,
                            unsigned short* __restrict__ out, int n4) {
  int i = blockIdx.x * 256 + threadIdx.x;
  if (i >= n4) return;
  float sc = scal[sidx];
  float4 v = ((const float4*)x)[i];
  ushort4 o;
  o.x = f2bf(fminf(fmaxf(rintf(v.x / sc), -127.f), 127.f));
  o.y = f2bf(fminf(fmaxf(rintf(v.y / sc), -127.f), 127.f));
  o.z = f2bf(fminf(fmaxf(rintf(v.z / sc), -127.f), 127.f));
  o.w = f2bf(fminf(fmaxf(rintf(v.w / sc), -127.f), 127.f));
  ((ushort4*)out)[i] = o;
}

// y selects which W; dst regions are contiguous (wq3 then wo)
__global__ void k_quant_w4(const float* __restrict__ w0, const float* __restrict__ w1,
                           const float* __restrict__ w2, const float* __restrict__ w3,
                           const float* __restrict__ scal, unsigned short* __restrict__ out) {
  const int y = blockIdx.y;
  const float* src = (y == 0) ? w0 : (y == 1) ? w1 : (y == 2) ? w2 : w3;
  const float sc = scal[1 + y];
  unsigned short* dst = out + (size_t)y * 1048576;
  int i = blockIdx.x * 256 + threadIdx.x;  // 262144 float4s
  float4 v = ((const float4*)src)[i];
  ushort4 o;
  o.x = f2bf(fminf(fmaxf(rintf(v.x / sc), -1.f), 1.f));
  o.y = f2bf(fminf(fmaxf(rintf(v.y / sc), -1.f), 1.f));
  o.z = f2bf(fminf(fmaxf(rintf(v.z / sc), -1.f), 1.f));
  o.w = f2bf(fminf(fmaxf(rintf(v.w / sc), -1.f), 1.f));
  ((ushort4*)dst)[i] = o;
}

// ---------------- GEMM: C[M][N] = A[M][1024] * B[N][1024]^T ----------------
// MODE 0: QKV proj (N=3072): scale, RoPE for q/k, write Qb/Kb(bf16)+Vf(f32) + q2/k2 row norms
// MODE 1: O proj (N=1024): scale, fp32 out
template <int MODE>
__launch_bounds__(256, 2)
__global__ void k_gemm(const unsigned short* __restrict__ Ag, const unsigned short* __restrict__ Bg,
                       const float* __restrict__ scal, const float* __restrict__ cosT,
                       const float* __restrict__ sinT, unsigned short* __restrict__ Qb,
                       unsigned short* __restrict__ Kb, float* __restrict__ Vf,
                       float* __restrict__ q2t, float* __restrict__ k2t, float* __restrict__ Co) {
  __shared__ alignas(16) unsigned short As[2][128 * 64];
  __shared__ alignas(16) unsigned short Bs[2][128 * 64];
  const int w = threadIdx.x >> 6, l = threadIdx.x & 63;
  const int mbase = blockIdx.y * 128, nbase = blockIdx.x * 128;

  const f32x4 vzero = {0.f, 0.f, 0.f, 0.f};
  f32x4 acc[4][4];
#pragma unroll
  for (int a = 0; a < 4; ++a)
#pragma unroll
    for (int b = 0; b < 4; ++b) acc[a][b] = vzero;

  const int srow = l >> 3;
  const int sxor = ((l & 7) << 4) ^ ((l >> 3) << 4);

  auto stage = [&](int kt, int buf) {
#pragma unroll
    for (int i = 0; i < 4; ++i) {
      int j = (w << 2) + i;
      int rowA = mbase + (j << 3) + srow;
      gload16((const char*)Ag + (size_t)rowA * 2048 + kt * 128 + sxor, (char*)&As[buf][0] + (j << 10));
      int rowB = nbase + (j << 3) + srow;
      gload16((const char*)Bg + (size_t)rowB * 2048 + kt * 128 + sxor, (char*)&Bs[buf][0] + (j << 10));
    }
  };

  const int rA0 = ((w >> 1) << 6) + (l & 15);
  const int rB0 = ((w & 1) << 6) + (l & 15);
  auto compute = [&](int buf) {
    const char* Ab = (const char*)&As[buf][0];
    const char* Bb = (const char*)&Bs[buf][0];
#pragma unroll
    for (int c = 0; c < 2; ++c) {
      const int colb = (c << 6) + ((l >> 4) << 4);
      short8 af[4], bf[4];
#pragma unroll
      for (int t = 0; t < 4; ++t) {
        const int ra = rA0 + (t << 4);
        af[t] = *(const short8*)(Ab + ra * 128 + (colb ^ ((ra & 7) << 4)));
        const int rb = rB0 + (t << 4);
        bf[t] = *(const short8*)(Bb + rb * 128 + (colb ^ ((rb & 7) << 4)));
      }
#pragma unroll
      for (int mt = 0; mt < 4; ++mt)
#pragma unroll
        for (int nt = 0; nt < 4; ++nt)
          acc[mt][nt] = __builtin_amdgcn_mfma_f32_16x16x32_bf16(af[mt], bf[nt], acc[mt][nt], 0, 0, 0);
    }
  };

  stage(0, 0);
  asm volatile("s_waitcnt vmcnt(0)" ::: "memory");
  __syncthreads();
  for (int kt = 0; kt < 16; ++kt) {
    const int cur = kt & 1;
    if (kt < 15) stage(kt + 1, cur ^ 1);
    compute(cur);
    asm volatile("s_waitcnt vmcnt(0)" ::: "memory");
    __syncthreads();
  }

  // epilogue  (C layout: col = lane&15, row = (lane>>4)*4 + reg)
  if constexpr (MODE == 0) {
    const int wm = w >> 1, wn = w & 1;
    const int gcolbase = nbase + wn * 64;
    const int section = gcolbase >> 10;  // 0=q 1=k 2=v
    const int h = (gcolbase & 1023) >> 6;
    const float sc = scal[0] * scal[1 + section];
    const int growbase = mbase + wm * 64;
    if (section < 2) {
      unsigned short* Outb = (section == 0) ? Qb : Kb;
      float* nrm = (section == 0) ? q2t : k2t;
#pragma unroll
      for (int mt = 0; mt < 4; ++mt)
#pragma unroll
        for (int r = 0; r < 4; ++r) {
          const int grow = growbase + mt * 16 + ((l >> 4) << 2) + r;
          const int b = grow >> 11, s = grow & 2047;
          const size_t ob = ((size_t)(b * 16 + h) * 2048 + s) * 64;
          float rsq = 0.f;
#pragma unroll
          for (int nt = 0; nt < 2; ++nt) {
            const int d = nt * 16 + (l & 15);
            const float v1 = acc[mt][nt][r] * sc;
            const float v2 = acc[mt][nt + 2][r] * sc;
            const float cv = cosT[s * 32 + d];
            const float sv = sinT[s * 32 + d];
            const unsigned short h1 = f2bf(v1 * cv - v2 * sv);
            const unsigned short h2 = f2bf(v2 * cv + v1 * sv);
            Outb[ob + d] = h1;
            Outb[ob + d + 32] = h2;
            const float o1 = bf2f(h1), o2 = bf2f(h2);
            rsq += o1 * o1 + o2 * o2;
          }
          // row sum of squares across the 16 lanes sharing this row
#pragma unroll
          for (int off = 1; off < 16; off <<= 1) rsq += __shfl_xor(rsq, off);
          if ((l & 15) == 0) nrm[(size_t)(b * 16 + h) * 2048 + s] = rsq;
        }
    } else {
#pragma unroll
      for (int mt = 0; mt < 4; ++mt)
#pragma unroll
        for (int r = 0; r < 4; ++r) {
          const int grow = growbase + mt * 16 + ((l >> 4) << 2) + r;
          const int b = grow >> 11, s = grow & 2047;
          const size_t ob = ((size_t)(b * 16 + h) * 2048 + s) * 64;
#pragma unroll
          for (int nt = 0; nt < 4; ++nt) Vf[ob + nt * 16 + (l & 15)] = acc[mt][nt][r] * sc;
        }
    }
  } else {
    const float sc = scal[4] * scal[5];
#pragma unroll
    for (int mt = 0; mt < 4; ++mt)
#pragma unroll
      for (int r = 0; r < 4; ++r) {
        const int grow = mbase + (w >> 1) * 64 + mt * 16 + ((l >> 4) << 2) + r;
#pragma unroll
        for (int nt = 0; nt < 4; ++nt) {
          const int gcol = nbase + (w & 1) * 64 + nt * 16 + (l & 15);
          Co[(size_t)grow * 1024 + gcol] = acc[mt][nt][r] * sc;
        }
      }
  }
}

// ---------------- k2max per head ----------------
__global__ void k_k2max(const float* __restrict__ k2t, float* __restrict__ k2m) {
  __shared__ float red[256];
  const int bh = blockIdx.x;
  float m = 0.f;
  for (int i = threadIdx.x; i < 2048; i += 256) m = fmaxf(m, k2t[(size_t)bh * 2048 + i]);
  red[threadIdx.x] = m;
  __syncthreads();
  for (int st = 128; st > 0; st >>= 1) {
    if ((int)threadIdx.x < st) red[threadIdx.x] = fmaxf(red[threadIdx.x], red[threadIdx.x + st]);
    __syncthreads();
  }
  if (threadIdx.x == 0) k2m[bh] = red[0];
}

// ---------------- V transpose + bf16 hi/lo split ----------------
__global__ void k_transpose_v(const float* __restrict__ Vf, unsigned short* __restrict__ Vthi,
                              unsigned short* __restrict__ Vtlo) {
  __shared__ float t[64][65];
  const int bh = blockIdx.x >> 5, st = blockIdx.x & 31;
  const float* src = Vf + ((size_t)bh * 2048 + st * 64) * 64;
  const int tid = threadIdx.x;
  for (int i = tid; i < 1024; i += 256) {
    float4 v = ((const float4*)src)[i];
    int row = i >> 4, c4 = (i & 15) << 2;
    t[row][c4] = v.x; t[row][c4 + 1] = v.y; t[row][c4 + 2] = v.z; t[row][c4 + 3] = v.w;
  }
  __syncthreads();
  const int d = tid >> 2, sp = (tid & 3) << 4;
  const size_t ob = ((size_t)bh * 64 + d) * 2048 + st * 64 + sp;
  short8 hv[2], lv[2];
#pragma unroll
  for (int j = 0; j < 16; ++j) {
    float f = t[sp + j][d];
    unsigned short hi = f2bf(f);
    unsigned short lo = f2bf(f - bf2f(hi));
    hv[j >> 3][j & 7] = (short)hi;
    lv[j >> 3][j & 7] = (short)lo;
  }
  *(short8*)(Vthi + ob) = hv[0];
  *(short8*)(Vthi + ob + 8) = hv[1];
  *(short8*)(Vtlo + ob) = lv[0];
  *(short8*)(Vtlo + ob + 8) = lv[1];
}

// ---------------- attention ----------------
__launch_bounds__(256, 2)
__global__ void k_attn(const unsigned short* __restrict__ Qb, const unsigned short* __restrict__ Kb,
                       const unsigned short* __restrict__ Vhi, const unsigned short* __restrict__ Vlo,
                       const float* __restrict__ q2t, const float* __restrict__ k2m,
                       float* __restrict__ Wout, float* __restrict__ Apre,
                       float* __restrict__ pmaxa) {
  __shared__ alignas(16) unsigned short Ks[2][64 * 64];
  __shared__ alignas(16) unsigned short Vhs[2][64 * 64];
  __shared__ alignas(16) unsigned short Vls[2][64 * 64];
  __shared__ alignas(16) unsigned int Ps[4][16 * 64];

  const int bh = blockIdx.x >> 5, qt = blockIdx.x & 31;
  const int w = threadIdx.x >> 6, l = threadIdx.x & 63;

  const unsigned short* Kg = Kb + (size_t)bh * S_ * D_;
  const unsigned short* Vhg = Vhi + (size_t)bh * D_ * S_;
  const unsigned short* Vlg = Vlo + (size_t)bh * D_ * S_;

  // Q fragments (A-operand): row = l&15
  short8 aq[2];
  {
    const int qrow_f = qt * 64 + w * 16 + (l & 15);
    const unsigned short* qp = Qb + (size_t)bh * S_ * D_ + (size_t)qrow_f * D_ + ((l >> 4) << 3);
    aq[0] = *(const short8*)qp;
    aq[1] = *(const short8*)(qp + 32);
  }

  // softmax shift: c_r = sqrt(q2_row * k2max)/8 >= all scores of this row (Cauchy-Schwarz)
  float cth[4];
  {
    const float km = k2m[bh];
#pragma unroll
    for (int r = 0; r < 4; ++r) {
      const int qr = qt * 64 + w * 16 + ((l >> 4) << 2) + r;
      cth[r] = sqrtf(q2t[(size_t)bh * 2048 + qr] * km) * 0.125f;
    }
  }

  const f32x4 vzero = {0.f, 0.f, 0.f, 0.f};
  const int kxor = ((l & 7) << 4) ^ ((l >> 3) << 4);
  const int lxor = ((l << 4) ^ ((l >> 3) << 4));

  auto stageK = [&](int kb, int buf) {
    const char* baseK = (const char*)(Kg + (size_t)kb * 64 * D_);
#pragma unroll
    for (int i = 0; i < 2; ++i) {
      int j = (w << 1) + i;
      gload16(baseK + (j << 10) + lxor, (char*)&Ks[buf][0] + (j << 10));
    }
  };
  auto stageB = [&](int kb, int buf) {
    const char* baseK = (const char*)(Kg + (size_t)kb * 64 * D_);
#pragma unroll
    for (int i = 0; i < 2; ++i) {
      int j = (w << 1) + i;
      gload16(baseK + (j << 10) + lxor, (char*)&Ks[buf][0] + (j << 10));
      const size_t voff = (size_t)(j * 8 + (l >> 3)) * (S_ * 2) + (size_t)kb * 128 + kxor;
      gload16((const char*)Vhg + voff, (char*)&Vhs[buf][0] + (j << 10));
      gload16((const char*)Vlg + voff, (char*)&Vls[buf][0] + (j << 10));
    }
  };
  auto qkt = [&](int buf, f32x4* sa) {
    const char* Kbase = (const char*)&Ks[buf][0];
#pragma unroll
    for (int c = 0; c < 2; ++c) {
      const int colb = (c << 6) + ((l >> 4) << 4);
      short8 bk[4];
#pragma unroll
      for (int ct = 0; ct < 4; ++ct) {
        const int rb = (ct << 4) + (l & 15);
        bk[ct] = *(const short8*)(Kbase + rb * 128 + (colb ^ ((rb & 7) << 4)));
      }
#pragma unroll
      for (int ct = 0; ct < 4; ++ct)
        sa[ct] = __builtin_amdgcn_mfma_f32_16x16x32_bf16(aq[c], bk[ct], sa[ct], 0, 0, 0);
    }
  };

  // ===== PASS A: per-thread sumexp with fixed shift (no shuffles in loop) =====
  float lt[4] = {0.f, 0.f, 0.f, 0.f};
  stageK(0, 0);
  asm volatile("s_waitcnt vmcnt(0)" ::: "memory");
  __syncthreads();
  for (int kb = 0; kb < 32; ++kb) {
    const int cur = kb & 1;
    if (kb < 31) stageK(kb + 1, cur ^ 1);
    f32x4 sa[4];
#pragma unroll
    for (int t = 0; t < 4; ++t) sa[t] = vzero;
    qkt(cur, sa);
#pragma unroll
    for (int r = 0; r < 4; ++r) {
      lt[r] += __expf(sa[0][r] * 0.125f - cth[r]) + __expf(sa[1][r] * 0.125f - cth[r]) +
               __expf(sa[2][r] * 0.125f - cth[r]) + __expf(sa[3][r] * 0.125f - cth[r]);
    }
    asm volatile("s_waitcnt vmcnt(0)" ::: "memory");
    __syncthreads();
  }

  // merge across the 16 lanes sharing each row
  float rl[4];
#pragma unroll
  for (int r = 0; r < 4; ++r) {
    float s = lt[r];
#pragma unroll
    for (int off = 1; off < 16; off <<= 1) s += __shfl_xor(s, off);
    rl[r] = 1.0f / s;
  }

  f32x4 oacc[4];
#pragma unroll
  for (int t = 0; t < 4; ++t) oacc[t] = vzero;
  unsigned int* Pw = &Ps[w][0];
  const size_t wb0 = (size_t)bh * S_ * S_;

  // ===== PASS B: p write + PV (split precision) =====
  stageB(0, 0);
  asm volatile("s_waitcnt vmcnt(0)" ::: "memory");
  __syncthreads();
  for (int kb = 0; kb < 32; ++kb) {
    const int cur = kb & 1;
    if (kb < 31) stageB(kb + 1, cur ^ 1);

    f32x4 sa[4];
#pragma unroll
    for (int t = 0; t < 4; ++t) sa[t] = vzero;
    qkt(cur, sa);

    // p = exp(s-c)/l -> pack hi/lo into per-wave LDS
#pragma unroll
    for (int ct = 0; ct < 4; ++ct) {
#pragma unroll
      for (int r = 0; r < 4; ++r) {
        const float p = __expf(sa[ct][r] * 0.125f - cth[r]) * rl[r];
        const unsigned short hi = f2bf(p);
        const unsigned short lo = f2bf(p - bf2f(hi));
        const int prow = ((l >> 4) << 2) + r;
        const int pcolb = (ct * 16 + (l & 15)) << 2;
        *(unsigned int*)((char*)Pw + prow * 256 + (pcolb ^ ((prow & 7) << 4))) =
            (((unsigned)hi) << 16) | (unsigned)lo;
      }
    }

    // coalesced attn-weight store reconstructed from the wave's P-tile
    {
      const size_t wrow0 = wb0 + (size_t)(qt * 64 + w * 16) * S_ + (size_t)kb * 64;
#pragma unroll
      for (int i = 0; i < 4; ++i) {
        const int prow = (i << 2) + (l >> 4);
        const int cb = (l & 15) << 4;
        const u32x4 u = *(const u32x4*)((const char*)Pw + prow * 256 + (cb ^ ((prow & 7) << 4)));
        float4 f;
        f.x = bf2f((unsigned short)(u[0] >> 16)) + bf2f((unsigned short)(u[0] & 0xffffu));
        f.y = bf2f((unsigned short)(u[1] >> 16)) + bf2f((unsigned short)(u[1] & 0xffffu));
        f.z = bf2f((unsigned short)(u[2] >> 16)) + bf2f((unsigned short)(u[2] & 0xffffu));
        f.w = bf2f((unsigned short)(u[3] >> 16)) + bf2f((unsigned short)(u[3] & 0xffffu));
        *(float4*)(Wout + wrow0 + (size_t)prow * S_ + ((l & 15) << 2)) = f;
      }
    }

    // PV: O += (p_hi+p_lo)*v_hi + p_hi*v_lo
#pragma unroll
    for (int c = 0; c < 2; ++c) {
      const int arow = l & 15;
      const int abyte = (c << 7) + ((l >> 4) << 5);
      const u32x4 u0 = *(const u32x4*)((const char*)Pw + arow * 256 + (abyte ^ ((arow & 7) << 4)));
      const u32x4 u1 =
          *(const u32x4*)((const char*)Pw + arow * 256 + ((abyte + 16) ^ ((arow & 7) << 4)));
      short8 ph, pl;
#pragma unroll
      for (int i2 = 0; i2 < 4; ++i2) {
        ph[i2] = (short)(u0[i2] >> 16);
        pl[i2] = (short)(u0[i2] & 0xffffu);
        ph[4 + i2] = (short)(u1[i2] >> 16);
        pl[4 + i2] = (short)(u1[i2] & 0xffffu);
      }
      const int colb = (c << 6) + ((l >> 4) << 4);
#pragma unroll
      for (int dt = 0; dt < 4; ++dt) {
        const int rv = (dt << 4) + (l & 15);
        const short8 vh = *(const short8*)((const char*)&Vhs[cur][0] + rv * 128 + (colb ^ ((rv & 7) << 4)));
        const short8 vl = *(const short8*)((const char*)&Vls[cur][0] + rv * 128 + (colb ^ ((rv & 7) << 4)));
        oacc[dt] = __builtin_amdgcn_mfma_f32_16x16x32_bf16(ph, vh, oacc[dt], 0, 0, 0);
        oacc[dt] = __builtin_amdgcn_mfma_f32_16x16x32_bf16(pl, vh, oacc[dt], 0, 0, 0);
        oacc[dt] = __builtin_amdgcn_mfma_f32_16x16x32_bf16(ph, vl, oacc[dt], 0, 0, 0);
      }
    }
    asm volatile("s_waitcnt vmcnt(0)" ::: "memory");
    __syncthreads();
  }

  const int b = bh >> 4, h = bh & 15;
  float am = 0.f;
#pragma unroll
  for (int dt = 0; dt < 4; ++dt)
#pragma unroll
    for (int r = 0; r < 4; ++r) {
      const int qr = qt * 64 + w * 16 + ((l >> 4) << 2) + r;
      Apre[(size_t)(b * S_ + qr) * DM_ + h * 64 + dt * 16 + (l & 15)] = oacc[dt][r];
      am = fmaxf(am, fabsf(oacc[dt][r]));
    }
  // block absmax -> pmaxa[blockIdx]
#pragma unroll
  for (int off = 1; off < 64; off <<= 1) am = fmaxf(am, __shfl_xor(am, off));
  __syncthreads();
  float* red = (float*)&Ps[0][0];
  if (l == 0) red[w] = am;
  __syncthreads();
  if (threadIdx.x == 0)
    pmaxa[blockIdx.x] = fmaxf(fmaxf(red[0], red[1]), fmaxf(red[2], red[3]));
}

// ---------------- launcher ----------------
extern "C" void kernel_launch(void* const* d_in, const int* in_sizes, int n_in, void* d_out,
                              int out_size, void* d_ws, size_t ws_size, hipStream_t stream) {
  const float* hidden = (const float*)d_in[0];
  const float* Wq = (const float*)d_in[1];
  const float* Wk = (const float*)d_in[2];
  const float* Wv = (const float*)d_in[3];
  const float* Wo = (const float*)d_in[4];
  float* out0 = (float*)d_out;
  float* out1 = out0 + OUT0_ELEMS;

  if (ws_size < WS_NEED) return;

  char* ws = (char*)d_ws;
  float* wsf = (float*)ws;
  float* pmaxx = (float*)(ws + OFF_PMAXX);
  float* psum = (float*)(ws + OFF_PSUM);
  float* pmaxa = (float*)(ws + OFF_PMAXA);
  float* k2mp = (float*)(ws + OFF_K2M);
  float* cosT = (float*)(ws + OFF_COS);
  float* sinT = (float*)(ws + OFF_SIN);
  float* q2p = (float*)(ws + OFF_Q2);
  float* k2p = (float*)(ws + OFF_K2);
  unsigned short* xq = (unsigned short*)(ws + OFF_XQ);
  unsigned short* wq3 = (unsigned short*)(ws + OFF_WQ3);
  unsigned short* wo = (unsigned short*)(ws + OFF_WO);
  unsigned short* Qbp = (unsigned short*)(ws + OFF_QB);
  unsigned short* Kbp = (unsigned short*)(ws + OFF_KB);
  float* Vfp = (float*)(ws + OFF_VF);
  unsigned short* Vthip = (unsigned short*)(ws + OFF_VTHI);
  unsigned short* Vtlop = (unsigned short*)(ws + OFF_VTLO);
  float* apre = (float*)(ws + OFF_APRE);
  unsigned short* aq16 = (unsigned short*)(ws + OFF_AQ);

  k_reduce5<<<dim3(128, 5), 256, 0, stream>>>(hidden, Wq, Wk, Wv, Wo, pmaxx, psum);
  k_finalize1<<<1, 64, 0, stream>>>(wsf);
  k_rope<<<256, 256, 0, stream>>>(cosT, sinT);
  k_quant_act<<<4096, 256, 0, stream>>>(hidden, wsf, 0, xq, 1048576);
  k_quant_w4<<<dim3(1024, 4), 256, 0, stream>>>(Wq, Wk, Wv, Wo, wsf, wq3);
  k_gemm<0><<<dim3(24, 32), 256, 0, stream>>>(xq, wq3, wsf, cosT, sinT, Qbp, Kbp, Vfp, q2p, k2p,
                                              nullptr);
  k_k2max<<<32, 256, 0, stream>>>(k2p, k2mp);
  k_transpose_v<<<1024, 256, 0, stream>>>(Vfp, Vthip, Vtlop);
  k_attn<<<1024, 256, 0, stream>>>(Qbp, Kbp, Vthip, Vtlop, q2p, k2mp, out1, apre, pmaxa);
  k_finalize2<<<1, 256, 0, stream>>>(pmaxa, wsf);
  k_quant_act<<<4096, 256, 0, stream>>>(apre, wsf, 5, aq16, 1048576);
  k_gemm<1><<<dim3(8, 32), 256, 0, stream>>>(aq16, wo, wsf, nullptr, nullptr, nullptr, nullptr,
                                             nullptr, nullptr, nullptr, out0);
  (void)wo; (void)in_sizes; (void)n_in; (void)out_size;
}